// Round 1
// 1867.501 us; speedup vs baseline: 1.1033x; 1.1033x over previous
//
#include <hip/hip_runtime.h>

// ---------------------------------------------------------------------------
// ReadingGCNStage: 3-layer bipartite GCN, bf16 MFMA (16x16x32).
// R3: 256x256-tile 8-phase GEMM (T2 swizzle + counted vmcnt + setprio) for the
// five bipartite GEMMs, split-K f32 partials + combine. Dense transforms stay
// on the proven 128x128 gemm64. M padding 20096 -> 20224 (79*256).
// ---------------------------------------------------------------------------

typedef __bf16 bf16_t;
typedef __attribute__((ext_vector_type(8))) __bf16 bf16x8;
typedef __attribute__((ext_vector_type(4))) __bf16 bf16x4;
typedef __attribute__((ext_vector_type(4))) float f32x4;

#define N_R 20000
#define N_S 5000
#define DD  512
#define MR_PAD 20224   // 79*256
#define MS_PAD 5120    // 20*256
#define KS_PAD 5056    // 79*64
#define KR_PAD 20224   // 316*64

// async global->LDS: per-lane global addr, LDS dest = wave-uniform base + lane*16B
__device__ __forceinline__ void gll16(const bf16_t* g, bf16_t* l) {
  __builtin_amdgcn_global_load_lds(
      (const __attribute__((address_space(1))) void*)g,
      (__attribute__((address_space(3))) void*)l, 16, 0, 0);
}

// ---------------- prep kernels ----------------

// A f32 [20000][5000] -> Ab bf16 [20224][5056] zero-padded; deg_r = rowsum+eps
__global__ __launch_bounds__(256) void conv_rowsum_A(
    const float* __restrict__ A, bf16_t* __restrict__ Ab, float* __restrict__ deg_r) {
  int r = blockIdx.x;
  int t = threadIdx.x;
  __shared__ float wsum[4];
  if (r < N_R) {
    const float4* Arow = (const float4*)(A + (size_t)r * N_S);  // 5000 = 4*1250
    float s = 0.f;
    for (int c4 = t; c4 < N_S / 4; c4 += 256) {
      float4 v = Arow[c4];
      s += v.x + v.y + v.z + v.w;
      bf16x4 pv;
      pv[0] = (bf16_t)v.x; pv[1] = (bf16_t)v.y; pv[2] = (bf16_t)v.z; pv[3] = (bf16_t)v.w;
      *(bf16x4*)(Ab + (size_t)r * KS_PAD + 4 * c4) = pv;
    }
    if (t < KS_PAD - N_S) Ab[(size_t)r * KS_PAD + N_S + t] = (bf16_t)0.f;
    for (int off = 32; off > 0; off >>= 1) s += __shfl_down(s, off, 64);
    if ((t & 63) == 0) wsum[t >> 6] = s;
    __syncthreads();
    if (t == 0) deg_r[r] = wsum[0] + wsum[1] + wsum[2] + wsum[3] + 1e-6f;
  } else {
    for (int c = t; c < KS_PAD; c += 256) Ab[(size_t)r * KS_PAD + c] = (bf16_t)0.f;
  }
}

__global__ void init_deg_s(float* __restrict__ deg_s) {
  int i = blockIdx.x * 256 + threadIdx.x;
  if (i < N_S) deg_s[i] = 1e-6f;
}

// Ab [20224][5056] -> At [5120][20224] (zero-padded both dims); deg_s += colsums
__global__ __launch_bounds__(256) void transpose_A_deg(
    const bf16_t* __restrict__ Ab, bf16_t* __restrict__ At, float* __restrict__ deg_s) {
  __shared__ float tile[64][65];
  __shared__ float csum[4][64];
  int rt = blockIdx.x * 64;   // 316 tiles -> 20224
  int st = blockIdx.y * 64;   // 80 tiles  -> 5120
  int tx = threadIdx.x & 63;
  int ty = threadIdx.x >> 6;
  int s = st + tx;
  float part = 0.f;
  for (int i = 0; i < 16; ++i) {
    int rr = ty * 16 + i;
    int r = rt + rr;
    float v = 0.f;
    if (r < N_R && s < KS_PAD) v = (float)Ab[(size_t)r * KS_PAD + s];
    tile[rr][tx] = v;
    part += v;
  }
  csum[ty][tx] = part;
  __syncthreads();
  if (ty == 0 && s < N_S)
    atomicAdd(&deg_s[s], csum[0][tx] + csum[1][tx] + csum[2][tx] + csum[3][tx]);
  for (int i = 0; i < 16; ++i) {
    int rr = ty * 16 + i;
    int r = rt + tx;
    if (r < KR_PAD) At[(size_t)(st + rr) * KR_PAD + r] = (bf16_t)tile[tx][rr];
  }
}

// dst[c][r] = (r<R ? src[r][c] : 0), r in [0,ldd)
template <typename SrcT>
__global__ __launch_bounds__(256) void transpose_to_bf16(
    const SrcT* __restrict__ src, int R, int C, bf16_t* __restrict__ dst, int ldd) {
  __shared__ float tile[64][65];
  int rt = blockIdx.x * 64;
  int ct = blockIdx.y * 64;
  int tx = threadIdx.x & 63;
  int ty = threadIdx.x >> 6;
  for (int i = 0; i < 16; ++i) {
    int rr = ty * 16 + i;
    int r = rt + rr;
    float v = 0.f;
    if (r < R) v = (float)src[(size_t)r * C + ct + tx];
    tile[rr][tx] = v;
  }
  __syncthreads();
  for (int i = 0; i < 16; ++i) {
    int rr = ty * 16 + i;
    int r = rt + tx;
    if (r < ldd) dst[(size_t)(ct + rr) * ldd + r] = (bf16_t)tile[tx][rr];
  }
}

// 12 512x512 weight transposes (z = l*4 + t)
__global__ __launch_bounds__(256) void transpose_weights(
    const float* __restrict__ Wr, const float* __restrict__ Ws,
    const float* __restrict__ Vr, const float* __restrict__ Vs,
    bf16_t* __restrict__ WT) {
  int z = blockIdx.z;
  int t4 = z & 3, l = z >> 2;
  const float* srcs[4] = {Wr, Ws, Vr, Vs};
  const float* src = srcs[t4] + (size_t)l * DD * DD;
  bf16_t* dst = WT + (size_t)z * DD * DD;
  __shared__ float tile[64][65];
  int rt = blockIdx.x * 64, ct = blockIdx.y * 64;
  int tx = threadIdx.x & 63, ty = threadIdx.x >> 6;
  for (int i = 0; i < 16; ++i) {
    int rr = ty * 16 + i;
    tile[rr][tx] = src[(size_t)(rt + rr) * DD + ct + tx];
  }
  __syncthreads();
  for (int i = 0; i < 16; ++i) {
    int rr = ty * 16 + i;
    dst[(size_t)(ct + rr) * DD + rt + tx] = (bf16_t)tile[tx][rr];
  }
}

// row-major f32 -> bf16 with row padding (C = 512)
__global__ __launch_bounds__(256) void conv_pad(
    const float* __restrict__ src, bf16_t* __restrict__ dst, int R, int Rp) {
  size_t i = (size_t)blockIdx.x * 256 + threadIdx.x;
  size_t tot = (size_t)Rp * DD;
  if (i < tot) {
    int r = (int)(i / DD);
    dst[i] = (r < R) ? (bf16_t)src[i] : (bf16_t)0.f;
  }
}

// sum S partial f32 buffers, divide by deg[row], write bf16 (pad rows -> 0)
__global__ __launch_bounds__(256) void combine_div(
    const float* __restrict__ part, int S, size_t stride,
    const float* __restrict__ deg, int Mreal, int Mpad, bf16_t* __restrict__ out) {
  size_t base = ((size_t)blockIdx.x * 256 + threadIdx.x) * 4;
  if (base >= (size_t)Mpad * DD) return;
  f32x4 s = *(const f32x4*)(part + base);
  for (int k = 1; k < S; ++k) s += *(const f32x4*)(part + (size_t)k * stride + base);
  int r = (int)(base >> 9);
  float inv = (r < Mreal) ? 1.0f / deg[r] : 0.f;
  bf16x4 o;
  o[0] = (bf16_t)(s[0] * inv); o[1] = (bf16_t)(s[1] * inv);
  o[2] = (bf16_t)(s[2] * inv); o[3] = (bf16_t)(s[3] * inv);
  *(bf16x4*)(out + base) = o;
}

// ---------------------------------------------------------------------------
// 256x256-tile BK=64 8-phase GEMM (B given as B^T [N][K], same ld as A).
// 8 waves (2M x 4N), per-wave 128x64 output. LDS 128 KiB: 2 bufs x (A,B) x
// [256 rows][64 elems], XOR-swizzled (elem ^= (row&7)<<3) via inverse-swizzled
// global_load_lds SOURCE + swizzled ds_read (rule: both-sides-or-neither).
// Counted vmcnt(4) twice per K-tile (never 0 in loop); setprio around MFMA.
// Writes f32 partials at Cpart + z*part_stride (combine_div finishes).
// Per-wave staging-op ledger (2 ops/phase, prologue 10):
//   need B-Q*(t)+A-Q0,Q2(t) before q1 -> covered by vmcnt(4) at prev q4;
//   need A-Q1,Q3(t) before q2        -> covered by vmcnt(4) at q1.
// Overwrite-issues land >=1 full phase after slot's last reader barrier.
// ---------------------------------------------------------------------------
__global__ __launch_bounds__(512, 2) void gemm256(
    const bf16_t* __restrict__ A, const bf16_t* __restrict__ B, int ld,
    int kt_total, int kt_chunk, float* __restrict__ Cpart, size_t part_stride) {
  __shared__ bf16_t As[2][256 * 64];
  __shared__ bf16_t Bs[2][256 * 64];
  const int tid = threadIdx.x;
  const int lane = tid & 63;
  const int wave = tid >> 6;            // 0..7
  const int bid = blockIdx.x;
  const int m0 = (bid >> 1) * 256;      // n fastest: y-pairs co-resident share A
  const int n0 = (bid & 1) * 256;
  const int z = blockIdx.y;
  const int ktb = z * kt_chunk;
  int kte = ktb + kt_chunk;
  if (kte > kt_total) kte = kt_total;
  if (ktb >= kte) return;
  const int wm = (wave >> 2) * 128;     // 2 M-waves
  const int wn = (wave & 3) * 64;       // 4 N-waves
  const int lr = lane & 15;
  const int quad = lane >> 4;
  const int rloc = lane >> 3;                 // 0..7: row within 8-row lane group
  const int cel = ((lane & 7) ^ rloc) * 8;    // inverse-swizzled source elem col

  // stage one 64-row quarter (q=0..3) of tile t into As/Bs[b]; 1 vm-op/wave
  auto SA = [&](int b, int q, int t) {
    int k0 = (t < kte ? t : kte - 1) * 64;
    gll16(A + (size_t)(m0 + q * 64 + wave * 8 + rloc) * ld + k0 + cel,
          &As[b][(q * 64 + wave * 8) * 64]);
  };
  auto SB = [&](int b, int q, int t) {
    int k0 = (t < kte ? t : kte - 1) * 64;
    gll16(B + (size_t)(n0 + q * 64 + wave * 8 + rloc) * ld + k0 + cel,
          &Bs[b][(q * 64 + wave * 8) * 64]);
  };

  f32x4 acc[8][4] = {};
  bf16x8 af[4], bf[4];

#define PHASE(BUF, MH, KS, READB, ...)                                           \
  {                                                                              \
    _Pragma("unroll")                                                            \
    for (int i = 0; i < 4; ++i) {                                                \
      int r = wm + (MH) * 64 + i * 16 + lr;                                      \
      af[i] = *(const bf16x8*)&As[BUF][r * 64 +                                  \
                                       (((KS) * 32 + quad * 8) ^ ((r & 7) * 8))];\
    }                                                                            \
    if (READB) {                                                                 \
      _Pragma("unroll")                                                          \
      for (int j = 0; j < 4; ++j) {                                              \
        int r = wn + j * 16 + lr;                                                \
        bf[j] = *(const bf16x8*)&Bs[BUF][r * 64 +                                \
                                       (((KS) * 32 + quad * 8) ^ ((r & 7) * 8))];\
      }                                                                          \
    }                                                                            \
    __VA_ARGS__;                                                                 \
    __builtin_amdgcn_s_barrier();                                                \
    asm volatile("s_waitcnt lgkmcnt(0)" ::: "memory");                           \
    __builtin_amdgcn_s_setprio(1);                                               \
    _Pragma("unroll")                                                            \
    for (int i = 0; i < 4; ++i)                                                  \
      _Pragma("unroll")                                                          \
      for (int j = 0; j < 4; ++j)                                                \
        acc[(MH) * 4 + i][j] = __builtin_amdgcn_mfma_f32_16x16x32_bf16(          \
            af[i], bf[j], acc[(MH) * 4 + i][j], 0, 0, 0);                        \
    __builtin_amdgcn_s_setprio(0);                                               \
  }

  // prologue: ops 1-4 B(t0) Q0..Q3, 5-6 A(t0) Q0,Q2, 7-8 A(t0) Q1,Q3,
  //           9-10 B(t0+1) Q0,Q1; vmcnt(4) -> ops 1-6 landed.
  SB(0, 0, ktb); SB(0, 1, ktb); SB(0, 2, ktb); SB(0, 3, ktb);
  SA(0, 0, ktb); SA(0, 2, ktb);
  SA(0, 1, ktb); SA(0, 3, ktb);
  SB(1, 0, ktb + 1); SB(1, 1, ktb + 1);
  asm volatile("s_waitcnt vmcnt(4)" ::: "memory");
  __builtin_amdgcn_s_barrier();

  const int nt = kte - ktb;
  for (int ti = 0; ti < nt; ++ti) {
    const int t = ktb + ti;
    const int buf = ti & 1;
    const int nb = buf ^ 1;
    // q1: reads ks0 (A mh0 + all B); stages B-Q2,Q3(t+1)
    PHASE(buf, 0, 0, 1, SB(nb, 2, t + 1); SB(nb, 3, t + 1));
    asm volatile("s_waitcnt vmcnt(4)" ::: "memory");   // A-Q1,Q3(t) landed
    __builtin_amdgcn_s_barrier();
    // q2: reads A mh1 ks0; stages A-Q0,Q2(t+1)
    PHASE(buf, 1, 0, 0, SA(nb, 0, t + 1); SA(nb, 2, t + 1));
    __builtin_amdgcn_s_barrier();
    // q3: reads ks1 (A mh0 + all B); stages A-Q1,Q3(t+1)
    PHASE(buf, 0, 1, 1, SA(nb, 1, t + 1); SA(nb, 3, t + 1));
    __builtin_amdgcn_s_barrier();
    // q4: reads A mh1 ks1; stages B-Q0,Q1(t+2) into this buf (B free after q3)
    PHASE(buf, 1, 1, 0, SB(buf, 0, t + 2); SB(buf, 1, t + 2));
    asm volatile("s_waitcnt vmcnt(4)" ::: "memory");   // B*(t+1)+A-Q0,Q2(t+1) landed
    __builtin_amdgcn_s_barrier();
  }
  asm volatile("s_waitcnt vmcnt(0)" ::: "memory");  // drain DMA before LDS dealloc
#undef PHASE

  // C/D layout: col = lane&15, row = quad*4 + reg
  float* P = Cpart + (size_t)z * part_stride;
#pragma unroll
  for (int ii = 0; ii < 8; ++ii)
#pragma unroll
    for (int j = 0; j < 4; ++j) {
      int c = n0 + wn + j * 16 + lr;
#pragma unroll
      for (int g = 0; g < 4; ++g) {
        int r = m0 + wm + ii * 16 + quad * 4 + g;
        P[(size_t)r * DD + c] = acc[ii][j][g];
      }
    }
}

// ---------------- 128x128 tile, BK=64 GEMM (dense transforms + fallback) ----
template <bool HAS2, int EPI>
__global__ __launch_bounds__(256) void gemm64(
    const bf16_t* __restrict__ A1, const bf16_t* __restrict__ B1, int kt1, int lda1, int ldb1,
    const bf16_t* __restrict__ A2, const bf16_t* __restrict__ B2, int kt2, int lda2, int ldb2,
    int kt_chunk,
    bf16_t* __restrict__ Cb, int Mreal, const float* __restrict__ deg,
    float* __restrict__ Cf, float* __restrict__ Cpart, size_t part_stride) {
  __shared__ bf16_t As[2 * 128 * 32];
  __shared__ bf16_t Bs[2 * 128 * 32];
  const int tid = threadIdx.x;
  const int lane = tid & 63;
  const int wave = tid >> 6;
  const int m0 = blockIdx.x * 128;
  const int n0 = blockIdx.y * 128;
  const int lrow = lane >> 2;
  const int lcol = (lane & 3) * 8;
  const int wm = (wave >> 1) * 64;
  const int wn = (wave & 1) * 64;
  const int lr = lane & 15;
  const int quad = lane >> 4;

  f32x4 acc[4][4] = {};

  const int ktot = kt1 + (HAS2 ? kt2 : 0);
  const int ktb = blockIdx.z * kt_chunk;
  const int kte = (ktb + kt_chunk < ktot) ? ktb + kt_chunk : ktot;

  for (int kt = ktb; kt < kte; ++kt) {
    const bf16_t* Ap; const bf16_t* Bp; int lda, ldb, k0;
    if (!HAS2 || kt < kt1) { Ap = A1; Bp = B1; lda = lda1; ldb = ldb1; k0 = kt * 64; }
    else                   { Ap = A2; Bp = B2; lda = lda2; ldb = ldb2; k0 = (kt - kt1) * 64; }
#pragma unroll
    for (int g = 0; g < 4; ++g) {
      const int h = g >> 1;
      const int rb = (g & 1) * 64 + wave * 16;
      gll16(Ap + (size_t)(m0 + rb + lrow) * lda + k0 + h * 32 + lcol,
            &As[h * 4096 + rb * 32]);
      gll16(Bp + (size_t)(n0 + rb + lrow) * ldb + k0 + h * 32 + lcol,
            &Bs[h * 4096 + rb * 32]);
    }
    __syncthreads();
    bf16x8 af[2][4], bq[2][4];
#pragma unroll
    for (int h = 0; h < 2; ++h)
#pragma unroll
      for (int i = 0; i < 4; ++i) {
        af[h][i] = *(const bf16x8*)&As[h * 4096 + (wm + i * 16 + lr) * 32 + quad * 8];
        bq[h][i] = *(const bf16x8*)&Bs[h * 4096 + (wn + i * 16 + lr) * 32 + quad * 8];
      }
#pragma unroll
    for (int h = 0; h < 2; ++h)
#pragma unroll
      for (int i = 0; i < 4; ++i)
#pragma unroll
        for (int j = 0; j < 4; ++j)
          acc[i][j] = __builtin_amdgcn_mfma_f32_16x16x32_bf16(af[h][i], bq[h][j], acc[i][j], 0, 0, 0);
    __syncthreads();
  }

  if (EPI == 2) {
    float* P = Cpart + blockIdx.z * part_stride;
#pragma unroll
    for (int i = 0; i < 4; ++i)
#pragma unroll
      for (int j = 0; j < 4; ++j) {
        int c = n0 + wn + j * 16 + lr;
#pragma unroll
        for (int g = 0; g < 4; ++g) {
          int r = m0 + wm + i * 16 + quad * 4 + g;
          P[(size_t)r * DD + c] = acc[i][j][g];
        }
      }
  } else {
#pragma unroll
    for (int i = 0; i < 4; ++i)
#pragma unroll
      for (int j = 0; j < 4; ++j) {
        int c = n0 + wn + j * 16 + lr;
#pragma unroll
        for (int g = 0; g < 4; ++g) {
          int r = m0 + wm + i * 16 + quad * 4 + g;
          if (r < Mreal) {
            float v = acc[i][j][g];
            if (EPI == 0) v /= deg[r];
            else v = fmaxf(v, 0.f);
            Cb[(size_t)r * DD + c] = (bf16_t)v;
            if (EPI == 1 && Cf != nullptr) Cf[(size_t)r * DD + c] = v;
          }
        }
      }
  }
}

// ---------------- host ----------------
extern "C" void kernel_launch(void* const* d_in, const int* in_sizes, int n_in,
                              void* d_out, int out_size, void* d_ws, size_t ws_size,
                              hipStream_t stream) {
  const float* h_s0 = (const float*)d_in[0];
  const float* A    = (const float*)d_in[1];
  const float* r_em = (const float*)d_in[2];
  const float* Wr   = (const float*)d_in[3];
  const float* Ws   = (const float*)d_in[4];
  const float* Vr   = (const float*)d_in[5];
  const float* Vs   = (const float*)d_in[6];
  float* out = (float*)d_out;

  char* p = (char*)d_ws;
  auto alloc = [&](size_t bytes) {
    char* q = p;
    p += (bytes + 255) & ~(size_t)255;
    return q;
  };
  bf16_t* Ab  = (bf16_t*)alloc((size_t)MR_PAD * KS_PAD * 2);
  bf16_t* At  = (bf16_t*)alloc((size_t)MS_PAD * KR_PAD * 2);
  bf16_t* hsT = (bf16_t*)alloc((size_t)DD * KS_PAD * 2);
  bf16_t* hrT = (bf16_t*)alloc((size_t)DD * KR_PAD * 2);
  bf16_t* WT  = (bf16_t*)alloc((size_t)12 * DD * DD * 2);
  bf16_t* hs_b[2] = {(bf16_t*)alloc((size_t)MS_PAD * DD * 2), (bf16_t*)alloc((size_t)MS_PAD * DD * 2)};
  bf16_t* hr_b[2] = {(bf16_t*)alloc((size_t)MR_PAD * DD * 2), (bf16_t*)alloc((size_t)MR_PAD * DD * 2)};
  bf16_t* mr_b = (bf16_t*)alloc((size_t)MR_PAD * DD * 2);
  bf16_t* ms_b = (bf16_t*)alloc((size_t)MS_PAD * DD * 2);
  float* deg_r = (float*)alloc((size_t)N_R * 4);
  float* deg_s = (float*)alloc((size_t)N_S * 4);
  size_t core_bytes = (size_t)(p - (char*)d_ws);
  // split-K partials (shared region, sequential use): max(3 x MR, 6 x MS)
  size_t part_stride_r = (size_t)MR_PAD * DD;            // elems
  size_t part_stride_s = (size_t)MS_PAD * DD;
  size_t part_bytes = (part_stride_r * 3 > part_stride_s * 6 ? part_stride_r * 3 : part_stride_s * 6) * 4;
  bool split_ok = (core_bytes + part_bytes + 256 <= ws_size);
  float* part = split_ok ? (float*)alloc(part_bytes) : nullptr;
  if (core_bytes > ws_size) return;  // can't run at all

  // ---- prep ----
  conv_rowsum_A<<<MR_PAD, 256, 0, stream>>>(A, Ab, deg_r);
  init_deg_s<<<(N_S + 255) / 256, 256, 0, stream>>>(deg_s);
  transpose_A_deg<<<dim3(316, 80), 256, 0, stream>>>(Ab, At, deg_s);
  transpose_to_bf16<float><<<dim3(79, 8), 256, 0, stream>>>(h_s0, N_S, DD, hsT, KS_PAD);
  transpose_to_bf16<float><<<dim3(316, 8), 256, 0, stream>>>(r_em, N_R, DD, hrT, KR_PAD);
  transpose_weights<<<dim3(8, 8, 12), 256, 0, stream>>>(Wr, Ws, Vr, Vs, WT);
  conv_pad<<<(MS_PAD * DD) / 256, 256, 0, stream>>>(h_s0, hs_b[0], N_S, MS_PAD);
  conv_pad<<<(MR_PAD * DD) / 256, 256, 0, stream>>>(r_em, hr_b[0], N_R, MR_PAD);

  const int ktA = KS_PAD / 64;  // 79
  const int ktT = KR_PAD / 64;  // 316

  // ---- layers ----
  int cur = 0;
  for (int l = 0; l < 3; ++l) {
    bf16_t* WrT = WT + ((size_t)l * 4 + 0) * DD * DD;
    bf16_t* WsT = WT + ((size_t)l * 4 + 1) * DD * DD;
    bf16_t* VrT = WT + ((size_t)l * 4 + 2) * DD * DD;
    bf16_t* VsT = WT + ((size_t)l * 4 + 3) * DD * DD;

    // m_r = (A @ h_s) / deg_r   [20224x512], K=5056
    if (split_ok) {
      gemm256<<<dim3(79 * 2, 3), 512, 0, stream>>>(
          Ab, hsT, KS_PAD, ktA, 27, part, part_stride_r);
      combine_div<<<MR_PAD * DD / 1024, 256, 0, stream>>>(
          part, 3, part_stride_r, deg_r, N_R, MR_PAD, mr_b);
    } else {
      gemm64<false, 0><<<dim3(158, 4, 1), 256, 0, stream>>>(
          Ab, hsT, ktA, KS_PAD, KS_PAD, nullptr, nullptr, 0, 0, 0,
          ktA, mr_b, N_R, deg_r, nullptr, nullptr, 0);
    }
    if (l < 2) {
      // m_s = (A^T @ h_r) / deg_s   [5120x512], K=20224
      if (split_ok) {
        gemm256<<<dim3(20 * 2, 6), 512, 0, stream>>>(
            At, hrT, KR_PAD, ktT, 53, part, part_stride_s);
        combine_div<<<MS_PAD * DD / 1024, 256, 0, stream>>>(
            part, 6, part_stride_s, deg_s, N_S, MS_PAD, ms_b);
      } else {
        gemm64<false, 0><<<dim3(40, 4, 1), 256, 0, stream>>>(
            At, hrT, ktT, KR_PAD, KR_PAD, nullptr, nullptr, 0, 0, 0,
            ktT, ms_b, N_S, deg_s, nullptr, nullptr, 0);
      }
    }
    // h_r' = relu(m_r@Ws + h_r@Wr)
    gemm64<true, 1><<<dim3(158, 4, 1), 256, 0, stream>>>(
        mr_b, WsT, 8, DD, DD, hr_b[cur], WrT, 8, DD, DD,
        16, hr_b[1 - cur], N_R, nullptr, (l == 2) ? out : nullptr, nullptr, 0);
    if (l < 2) {
      // h_s' = relu(m_s@Vr + h_s@Vs)
      gemm64<true, 1><<<dim3(40, 4, 1), 256, 0, stream>>>(
          ms_b, VrT, 8, DD, DD, hs_b[cur], VsT, 8, DD, DD,
          16, hs_b[1 - cur], N_S, nullptr, nullptr, nullptr, 0);
      transpose_to_bf16<bf16_t><<<dim3(316, 8), 256, 0, stream>>>(hr_b[1 - cur], N_R, DD, hrT, KR_PAD);
      transpose_to_bf16<bf16_t><<<dim3(79, 8), 256, 0, stream>>>(hs_b[1 - cur], N_S, DD, hsT, KS_PAD);
    }
    cur = 1 - cur;
  }
}

// Round 2
// 1650.935 us; speedup vs baseline: 1.2480x; 1.1312x over previous
//
#include <hip/hip_runtime.h>

// ---------------------------------------------------------------------------
// ReadingGCNStage: 3-layer bipartite GCN, bf16 MFMA (16x16x32).
// R4: keep the verified 8-phase gemm256 schedule; switch split-K partials to
// bf16 (halves combine traffic), fuse independent dispatches via blockIdx
// decode (m_r+m_s big GEMM, combines, dense transforms, transposes, pad+init),
// and vectorize the transpose kernels (16B global IO). 30 -> 16 dispatches.
// ---------------------------------------------------------------------------

typedef __bf16 bf16_t;
typedef __attribute__((ext_vector_type(8))) __bf16 bf16x8;
typedef __attribute__((ext_vector_type(4))) __bf16 bf16x4;
typedef __attribute__((ext_vector_type(4))) float f32x4;

#define N_R 20000
#define N_S 5000
#define DD  512
#define MR_PAD 20224   // 79*256
#define MS_PAD 5120    // 20*256
#define KS_PAD 5056    // 79*64
#define KR_PAD 20224   // 316*64

// async global->LDS: per-lane global addr, LDS dest = wave-uniform base + lane*16B
__device__ __forceinline__ void gll16(const bf16_t* g, bf16_t* l) {
  __builtin_amdgcn_global_load_lds(
      (const __attribute__((address_space(1))) void*)g,
      (__attribute__((address_space(3))) void*)l, 16, 0, 0);
}

// ---------------- prep kernels ----------------

// A f32 [20000][5000] -> Ab bf16 [20224][5056] zero-padded; deg_r = rowsum+eps
__global__ __launch_bounds__(256) void conv_rowsum_A(
    const float* __restrict__ A, bf16_t* __restrict__ Ab, float* __restrict__ deg_r) {
  int r = blockIdx.x;
  int t = threadIdx.x;
  __shared__ float wsum[4];
  if (r < N_R) {
    const float4* Arow = (const float4*)(A + (size_t)r * N_S);  // 5000 = 4*1250
    float s = 0.f;
    for (int c4 = t; c4 < N_S / 4; c4 += 256) {
      float4 v = Arow[c4];
      s += v.x + v.y + v.z + v.w;
      bf16x4 pv;
      pv[0] = (bf16_t)v.x; pv[1] = (bf16_t)v.y; pv[2] = (bf16_t)v.z; pv[3] = (bf16_t)v.w;
      *(bf16x4*)(Ab + (size_t)r * KS_PAD + 4 * c4) = pv;
    }
    if (t < KS_PAD - N_S) Ab[(size_t)r * KS_PAD + N_S + t] = (bf16_t)0.f;
    for (int off = 32; off > 0; off >>= 1) s += __shfl_down(s, off, 64);
    if ((t & 63) == 0) wsum[t >> 6] = s;
    __syncthreads();
    if (t == 0) deg_r[r] = wsum[0] + wsum[1] + wsum[2] + wsum[3] + 1e-6f;
  } else {
    for (int c = t; c < KS_PAD; c += 256) Ab[(size_t)r * KS_PAD + c] = (bf16_t)0.f;
  }
}

// fused: pad r_em -> hr_b0, pad h_s0 -> hs_b0, init deg_s
__global__ __launch_bounds__(256) void conv_pad2(
    const float* __restrict__ r_em, bf16_t* __restrict__ hr0,
    const float* __restrict__ h_s0, bf16_t* __restrict__ hs0,
    float* __restrict__ deg_s) {
  size_t i = (size_t)blockIdx.x * 256 + threadIdx.x;
  const size_t totR = (size_t)MR_PAD * DD;
  const size_t totS = (size_t)MS_PAD * DD;
  if (i < totR) {
    int r = (int)(i >> 9);
    hr0[i] = (r < N_R) ? (bf16_t)r_em[i] : (bf16_t)0.f;
  } else if (i < totR + totS) {
    size_t j = i - totR;
    int r = (int)(j >> 9);
    hs0[j] = (r < N_S) ? (bf16_t)h_s0[j] : (bf16_t)0.f;
  } else {
    size_t j = i - totR - totS;
    if (j < N_S) deg_s[j] = 1e-6f;
  }
}

// Ab [20224][5056] -> At [5120][20224] (zero-padded both dims); deg_s += colsums
// vectorized: 16B loads, 16B stores through f32 LDS tile.
__global__ __launch_bounds__(256) void transpose_A_deg(
    const bf16_t* __restrict__ Ab, bf16_t* __restrict__ At, float* __restrict__ deg_s) {
  __shared__ float tile[64][65];
  int rt = blockIdx.x * 64;   // 316 tiles -> 20224 (At cols)
  int st = blockIdx.y * 64;   // 80 tiles  -> 5120  (At rows)
  int t = threadIdx.x;
  const bool inA = (st < KS_PAD);   // s-tiles are 64-aligned: fully in or fully out
  int row = t >> 3;                 // 0..31
  int c = (t & 7) * 8;
#pragma unroll
  for (int k = 0; k < 2; ++k) {
    int rr = row + k * 32;
    if (inA) {
      bf16x8 v = *(const bf16x8*)(Ab + (size_t)(rt + rr) * KS_PAD + st + c);
#pragma unroll
      for (int j = 0; j < 8; ++j) tile[rr][c + j] = (float)v[j];
    } else {
#pragma unroll
      for (int j = 0; j < 8; ++j) tile[rr][c + j] = 0.f;
    }
  }
  __syncthreads();
  if (t < 64 && inA && st + t < N_S) {
    float s = 0.f;
#pragma unroll 8
    for (int r = 0; r < 64; ++r) s += tile[r][t];
    atomicAdd(&deg_s[st + t], s);
  }
  int sl = t >> 2;            // 0..63: At row within tile
  int r0 = (t & 3) * 16;      // 16-col chunk
  bf16x8 w0, w1;
#pragma unroll
  for (int i = 0; i < 8; ++i) w0[i] = (bf16_t)tile[r0 + i][sl];
#pragma unroll
  for (int i = 0; i < 8; ++i) w1[i] = (bf16_t)tile[r0 + 8 + i][sl];
  *(bf16x8*)(At + (size_t)(st + sl) * KR_PAD + rt + r0) = w0;
  *(bf16x8*)(At + (size_t)(st + sl) * KR_PAD + rt + r0 + 8) = w1;
}

// 8-float row loader (vectorized global read)
__device__ __forceinline__ void load8f(const float* p, float* f) {
  float4 a = *(const float4*)p;
  float4 b = *(const float4*)(p + 4);
  f[0] = a.x; f[1] = a.y; f[2] = a.z; f[3] = a.w;
  f[4] = b.x; f[5] = b.y; f[6] = b.z; f[7] = b.w;
}
__device__ __forceinline__ void load8f(const bf16_t* p, float* f) {
  bf16x8 v = *(const bf16x8*)p;
#pragma unroll
  for (int j = 0; j < 8; ++j) f[j] = (float)v[j];
}

// fused dual transpose: dst[c][r] = (r<R ? src[r][c] : 0), C = 512, vectorized
template <typename SrcT>
__global__ __launch_bounds__(256) void transpose2_to_bf16(
    const SrcT* __restrict__ s1, int R1, bf16_t* __restrict__ d1, int ldd1, int nbx1, int nb1,
    const SrcT* __restrict__ s2, int R2, bf16_t* __restrict__ d2, int ldd2, int nbx2) {
  int bid = blockIdx.x;
  const SrcT* src; int R; bf16_t* dst; int ldd, nbx;
  if (bid < nb1) { src = s1; R = R1; dst = d1; ldd = ldd1; nbx = nbx1; }
  else { bid -= nb1; src = s2; R = R2; dst = d2; ldd = ldd2; nbx = nbx2; }
  int rt = (bid % nbx) * 64;
  int ct = (bid / nbx) * 64;
  __shared__ float tile[64][65];
  int t = threadIdx.x;
  int row = t >> 3;
  int c = (t & 7) * 8;
#pragma unroll
  for (int k = 0; k < 2; ++k) {
    int rr = row + k * 32;
    int r = rt + rr;
    float f[8];
    if (r < R) load8f(src + (size_t)r * DD + ct + c, f);
    else {
#pragma unroll
      for (int j = 0; j < 8; ++j) f[j] = 0.f;
    }
#pragma unroll
    for (int j = 0; j < 8; ++j) tile[rr][c + j] = f[j];
  }
  __syncthreads();
  int sl = t >> 2;
  int r0 = (t & 3) * 16;
  bf16x8 w0, w1;
#pragma unroll
  for (int i = 0; i < 8; ++i) w0[i] = (bf16_t)tile[r0 + i][sl];
#pragma unroll
  for (int i = 0; i < 8; ++i) w1[i] = (bf16_t)tile[r0 + 8 + i][sl];
  *(bf16x8*)(dst + (size_t)(ct + sl) * ldd + rt + r0) = w0;
  *(bf16x8*)(dst + (size_t)(ct + sl) * ldd + rt + r0 + 8) = w1;
}

// 12 512x512 weight transposes (z = l*4 + t)
__global__ __launch_bounds__(256) void transpose_weights(
    const float* __restrict__ Wr, const float* __restrict__ Ws,
    const float* __restrict__ Vr, const float* __restrict__ Vs,
    bf16_t* __restrict__ WT) {
  int z = blockIdx.z;
  int t4 = z & 3, l = z >> 2;
  const float* srcs[4] = {Wr, Ws, Vr, Vs};
  const float* src = srcs[t4] + (size_t)l * DD * DD;
  bf16_t* dst = WT + (size_t)z * DD * DD;
  __shared__ float tile[64][65];
  int rt = blockIdx.x * 64, ct = blockIdx.y * 64;
  int tx = threadIdx.x & 63, ty = threadIdx.x >> 6;
  for (int i = 0; i < 16; ++i) {
    int rr = ty * 16 + i;
    tile[rr][tx] = src[(size_t)(rt + rr) * DD + ct + tx];
  }
  __syncthreads();
  for (int i = 0; i < 16; ++i) {
    int rr = ty * 16 + i;
    dst[(size_t)(ct + rr) * DD + rt + tx] = (bf16_t)tile[tx][rr];
  }
}

// fused dual combine: sum S bf16 partial slabs, /deg[row], write bf16
__global__ __launch_bounds__(256) void combine2(
    const bf16_t* __restrict__ p1, int S1, size_t st1, const float* __restrict__ deg1,
    int M1, bf16_t* __restrict__ o1, int nb1,
    const bf16_t* __restrict__ p2, int S2, size_t st2, const float* __restrict__ deg2,
    int M2, bf16_t* __restrict__ o2) {
  int bid = blockIdx.x;
  const bf16_t* p; int S; size_t st; const float* deg; int M; bf16_t* o;
  if (bid < nb1) { p = p1; S = S1; st = st1; deg = deg1; M = M1; o = o1; }
  else { bid -= nb1; p = p2; S = S2; st = st2; deg = deg2; M = M2; o = o2; }
  size_t base = ((size_t)bid * 256 + threadIdx.x) * 8;
  float acc[8] = {};
  for (int k = 0; k < S; ++k) {
    bf16x8 v = *(const bf16x8*)(p + (size_t)k * st + base);
#pragma unroll
    for (int j = 0; j < 8; ++j) acc[j] += (float)v[j];
  }
  int r = (int)(base >> 9);
  float inv = (r < M) ? 1.0f / deg[r] : 0.f;
  bf16x8 w;
#pragma unroll
  for (int j = 0; j < 8; ++j) w[j] = (bf16_t)(acc[j] * inv);
  *(bf16x8*)(o + base) = w;
}

// ---------------------------------------------------------------------------
// 256x256-tile BK=64 8-phase GEMM (B given as B^T [N][K], same ld as A).
// Dual-job dispatch via blockIdx decode (job1 first: put the longer-K job
// there so long blocks start early). Schedule identical to R3 (verified):
// T2 swizzle via inverse-swizzled gll16 source + swizzled ds_read, counted
// vmcnt(4) twice per K-tile, setprio around MFMA. Partials now bf16.
// ---------------------------------------------------------------------------
__global__ __launch_bounds__(512, 2) void gemm256d(
    const bf16_t* __restrict__ A1, const bf16_t* __restrict__ B1, int ld1,
    int kt1, int chunk1, bf16_t* __restrict__ P1, size_t ps1, int nx1, int nb1,
    const bf16_t* __restrict__ A2, const bf16_t* __restrict__ B2, int ld2,
    int kt2, int chunk2, bf16_t* __restrict__ P2, size_t ps2, int nx2) {
  __shared__ bf16_t As[2][256 * 64];
  __shared__ bf16_t Bs[2][256 * 64];
  int bid = blockIdx.x;
  const bf16_t* A; const bf16_t* B; bf16_t* P;
  int ld, kt_total, chunk, nx; size_t ps;
  if (bid < nb1) { A = A1; B = B1; ld = ld1; kt_total = kt1; chunk = chunk1; P = P1; ps = ps1; nx = nx1; }
  else { bid -= nb1; A = A2; B = B2; ld = ld2; kt_total = kt2; chunk = chunk2; P = P2; ps = ps2; nx = nx2; }
  const int bx = bid % nx;
  const int z  = bid / nx;
  const int m0 = (bx >> 1) * 256;       // n fastest: adjacent blocks share A rows
  const int n0 = (bx & 1) * 256;
  const int ktb = z * chunk;
  int kte = ktb + chunk;
  if (kte > kt_total) kte = kt_total;
  if (ktb >= kte) return;
  const int tid = threadIdx.x;
  const int lane = tid & 63;
  const int wave = tid >> 6;            // 0..7
  const int wm = (wave >> 2) * 128;     // 2 M-waves
  const int wn = (wave & 3) * 64;       // 4 N-waves
  const int lr = lane & 15;
  const int quad = lane >> 4;
  const int rloc = lane >> 3;                 // 0..7: row within 8-row lane group
  const int cel = ((lane & 7) ^ rloc) * 8;    // inverse-swizzled source elem col

  // stage one 64-row quarter (q=0..3) of tile t into As/Bs[b]; 1 vm-op/wave
  auto SA = [&](int b, int q, int t) {
    int k0 = (t < kte ? t : kte - 1) * 64;
    gll16(A + (size_t)(m0 + q * 64 + wave * 8 + rloc) * ld + k0 + cel,
          &As[b][(q * 64 + wave * 8) * 64]);
  };
  auto SB = [&](int b, int q, int t) {
    int k0 = (t < kte ? t : kte - 1) * 64;
    gll16(B + (size_t)(n0 + q * 64 + wave * 8 + rloc) * ld + k0 + cel,
          &Bs[b][(q * 64 + wave * 8) * 64]);
  };

  f32x4 acc[8][4] = {};
  bf16x8 af[4], bf[4];

#define PHASE(BUF, MH, KS, READB, ...)                                           \
  {                                                                              \
    _Pragma("unroll")                                                            \
    for (int i = 0; i < 4; ++i) {                                                \
      int r = wm + (MH) * 64 + i * 16 + lr;                                      \
      af[i] = *(const bf16x8*)&As[BUF][r * 64 +                                  \
                                       (((KS) * 32 + quad * 8) ^ ((r & 7) * 8))];\
    }                                                                            \
    if (READB) {                                                                 \
      _Pragma("unroll")                                                          \
      for (int j = 0; j < 4; ++j) {                                              \
        int r = wn + j * 16 + lr;                                                \
        bf[j] = *(const bf16x8*)&Bs[BUF][r * 64 +                                \
                                       (((KS) * 32 + quad * 8) ^ ((r & 7) * 8))];\
      }                                                                          \
    }                                                                            \
    __VA_ARGS__;                                                                 \
    __builtin_amdgcn_s_barrier();                                                \
    asm volatile("s_waitcnt lgkmcnt(0)" ::: "memory");                           \
    __builtin_amdgcn_s_setprio(1);                                               \
    _Pragma("unroll")                                                            \
    for (int i = 0; i < 4; ++i)                                                  \
      _Pragma("unroll")                                                          \
      for (int j = 0; j < 4; ++j)                                                \
        acc[(MH) * 4 + i][j] = __builtin_amdgcn_mfma_f32_16x16x32_bf16(          \
            af[i], bf[j], acc[(MH) * 4 + i][j], 0, 0, 0);                        \
    __builtin_amdgcn_s_setprio(0);                                               \
  }

  // prologue: ops 1-4 B(t0) Q0..Q3, 5-6 A(t0) Q0,Q2, 7-8 A(t0) Q1,Q3,
  //           9-10 B(t0+1) Q0,Q1; vmcnt(4) -> ops 1-6 landed.
  SB(0, 0, ktb); SB(0, 1, ktb); SB(0, 2, ktb); SB(0, 3, ktb);
  SA(0, 0, ktb); SA(0, 2, ktb);
  SA(0, 1, ktb); SA(0, 3, ktb);
  SB(1, 0, ktb + 1); SB(1, 1, ktb + 1);
  asm volatile("s_waitcnt vmcnt(4)" ::: "memory");
  __builtin_amdgcn_s_barrier();

  const int nt = kte - ktb;
  for (int ti = 0; ti < nt; ++ti) {
    const int t = ktb + ti;
    const int buf = ti & 1;
    const int nb = buf ^ 1;
    // q1: reads ks0 (A mh0 + all B); stages B-Q2,Q3(t+1)
    PHASE(buf, 0, 0, 1, SB(nb, 2, t + 1); SB(nb, 3, t + 1));
    asm volatile("s_waitcnt vmcnt(4)" ::: "memory");   // A-Q1,Q3(t) landed
    __builtin_amdgcn_s_barrier();
    // q2: reads A mh1 ks0; stages A-Q0,Q2(t+1)
    PHASE(buf, 1, 0, 0, SA(nb, 0, t + 1); SA(nb, 2, t + 1));
    __builtin_amdgcn_s_barrier();
    // q3: reads ks1 (A mh0 + all B); stages A-Q1,Q3(t+1)
    PHASE(buf, 0, 1, 1, SA(nb, 1, t + 1); SA(nb, 3, t + 1));
    __builtin_amdgcn_s_barrier();
    // q4: reads A mh1 ks1; stages B-Q0,Q1(t+2) into this buf (B free after q3)
    PHASE(buf, 1, 1, 0, SB(buf, 0, t + 2); SB(buf, 1, t + 2));
    asm volatile("s_waitcnt vmcnt(4)" ::: "memory");   // B*(t+1)+A-Q0,Q2(t+1) landed
    __builtin_amdgcn_s_barrier();
  }
  asm volatile("s_waitcnt vmcnt(0)" ::: "memory");  // drain DMA before LDS dealloc
#undef PHASE

  // C/D layout: col = lane&15, row = quad*4 + reg; bf16 partial store
  bf16_t* Pz = P + (size_t)z * ps;
#pragma unroll
  for (int ii = 0; ii < 8; ++ii)
#pragma unroll
    for (int j = 0; j < 4; ++j) {
      int c = n0 + wn + j * 16 + lr;
#pragma unroll
      for (int g = 0; g < 4; ++g) {
        int r = m0 + wm + ii * 16 + quad * 4 + g;
        Pz[(size_t)r * DD + c] = (bf16_t)acc[ii][j][g];
      }
    }
}

// ---------------- 128x128-tile dense transform: relu(Aa@Ba + Ab@Bb) ----------
// dual-job dispatch; kt fixed 8+8, all ld = 512. job1 may also write f32 Cf.
__global__ __launch_bounds__(256) void gemm64_dual(
    const bf16_t* __restrict__ Aa1, const bf16_t* __restrict__ Ba1,
    const bf16_t* __restrict__ Ab1, const bf16_t* __restrict__ Bb1,
    bf16_t* __restrict__ C1, int M1, float* __restrict__ Cf1, int nx1, int nb1,
    const bf16_t* __restrict__ Aa2, const bf16_t* __restrict__ Ba2,
    const bf16_t* __restrict__ Ab2, const bf16_t* __restrict__ Bb2,
    bf16_t* __restrict__ C2, int M2, int nx2) {
  __shared__ bf16_t As[2 * 128 * 32];
  __shared__ bf16_t Bs[2 * 128 * 32];
  int bid = blockIdx.x;
  const bf16_t *Aa, *Ba, *Abp, *Bb; bf16_t* C; float* Cf; int M, nx;
  if (bid < nb1) { Aa = Aa1; Ba = Ba1; Abp = Ab1; Bb = Bb1; C = C1; M = M1; Cf = Cf1; nx = nx1; }
  else { bid -= nb1; Aa = Aa2; Ba = Ba2; Abp = Ab2; Bb = Bb2; C = C2; M = M2; Cf = nullptr; nx = nx2; }
  const int m0 = (bid % nx) * 128;
  const int n0 = (bid / nx) * 128;
  const int tid = threadIdx.x;
  const int lane = tid & 63;
  const int wave = tid >> 6;
  const int lrow = lane >> 2;
  const int lcol = (lane & 3) * 8;
  const int wm = (wave >> 1) * 64;
  const int wn = (wave & 1) * 64;
  const int lr = lane & 15;
  const int quad = lane >> 4;

  f32x4 acc[4][4] = {};

  for (int kt = 0; kt < 16; ++kt) {
    const bf16_t* Ap = (kt < 8) ? Aa : Abp;
    const bf16_t* Bp = (kt < 8) ? Ba : Bb;
    const int k0 = (kt & 7) * 64;
#pragma unroll
    for (int g = 0; g < 4; ++g) {
      const int h = g >> 1;
      const int rb = (g & 1) * 64 + wave * 16;
      gll16(Ap + (size_t)(m0 + rb + lrow) * DD + k0 + h * 32 + lcol,
            &As[h * 4096 + rb * 32]);
      gll16(Bp + (size_t)(n0 + rb + lrow) * DD + k0 + h * 32 + lcol,
            &Bs[h * 4096 + rb * 32]);
    }
    __syncthreads();
    bf16x8 af[2][4], bq[2][4];
#pragma unroll
    for (int h = 0; h < 2; ++h)
#pragma unroll
      for (int i = 0; i < 4; ++i) {
        af[h][i] = *(const bf16x8*)&As[h * 4096 + (wm + i * 16 + lr) * 32 + quad * 8];
        bq[h][i] = *(const bf16x8*)&Bs[h * 4096 + (wn + i * 16 + lr) * 32 + quad * 8];
      }
#pragma unroll
    for (int h = 0; h < 2; ++h)
#pragma unroll
      for (int i = 0; i < 4; ++i)
#pragma unroll
        for (int j = 0; j < 4; ++j)
          acc[i][j] = __builtin_amdgcn_mfma_f32_16x16x32_bf16(af[h][i], bq[h][j], acc[i][j], 0, 0, 0);
    __syncthreads();
  }

#pragma unroll
  for (int i = 0; i < 4; ++i)
#pragma unroll
    for (int j = 0; j < 4; ++j) {
      int c = n0 + wn + j * 16 + lr;
#pragma unroll
      for (int g = 0; g < 4; ++g) {
        int r = m0 + wm + i * 16 + quad * 4 + g;
        if (r < M) {
          float v = fmaxf(acc[i][j][g], 0.f);
          C[(size_t)r * DD + c] = (bf16_t)v;
          if (Cf != nullptr) Cf[(size_t)r * DD + c] = v;
        }
      }
    }
}

// ---------------- host ----------------
extern "C" void kernel_launch(void* const* d_in, const int* in_sizes, int n_in,
                              void* d_out, int out_size, void* d_ws, size_t ws_size,
                              hipStream_t stream) {
  const float* h_s0 = (const float*)d_in[0];
  const float* A    = (const float*)d_in[1];
  const float* r_em = (const float*)d_in[2];
  const float* Wr   = (const float*)d_in[3];
  const float* Ws   = (const float*)d_in[4];
  const float* Vr   = (const float*)d_in[5];
  const float* Vs   = (const float*)d_in[6];
  float* out = (float*)d_out;

  char* p = (char*)d_ws;
  auto alloc = [&](size_t bytes) {
    char* q = p;
    p += (bytes + 255) & ~(size_t)255;
    return q;
  };
  bf16_t* Ab  = (bf16_t*)alloc((size_t)MR_PAD * KS_PAD * 2);
  bf16_t* At  = (bf16_t*)alloc((size_t)MS_PAD * KR_PAD * 2);
  bf16_t* hsT = (bf16_t*)alloc((size_t)DD * KS_PAD * 2);
  bf16_t* hrT = (bf16_t*)alloc((size_t)DD * KR_PAD * 2);
  bf16_t* WT  = (bf16_t*)alloc((size_t)12 * DD * DD * 2);
  bf16_t* hs_b[2] = {(bf16_t*)alloc((size_t)MS_PAD * DD * 2), (bf16_t*)alloc((size_t)MS_PAD * DD * 2)};
  bf16_t* hr_b[2] = {(bf16_t*)alloc((size_t)MR_PAD * DD * 2), (bf16_t*)alloc((size_t)MR_PAD * DD * 2)};
  bf16_t* mr_b = (bf16_t*)alloc((size_t)MR_PAD * DD * 2);
  bf16_t* ms_b = (bf16_t*)alloc((size_t)MS_PAD * DD * 2);
  float* deg_r = (float*)alloc((size_t)N_R * 4);
  float* deg_s = (float*)alloc((size_t)N_S * 4);
  const size_t ps_r = (size_t)MR_PAD * DD;   // partial slab stride (elems)
  const size_t ps_s = (size_t)MS_PAD * DD;
  bf16_t* part_r = (bf16_t*)alloc(ps_r * 3 * 2);   // z=3 slabs, bf16
  bf16_t* part_s = (bf16_t*)alloc(ps_s * 7 * 2);   // z=7 slabs, bf16
  if ((size_t)(p - (char*)d_ws) > ws_size) return;  // can't run

  // ---- prep (5 dispatches + weights) ----
  conv_rowsum_A<<<MR_PAD, 256, 0, stream>>>(A, Ab, deg_r);
  {
    size_t tot = (size_t)MR_PAD * DD + (size_t)MS_PAD * DD + N_S;
    conv_pad2<<<(unsigned)((tot + 255) / 256), 256, 0, stream>>>(r_em, hr_b[0], h_s0, hs_b[0], deg_s);
  }
  transpose_A_deg<<<dim3(316, 80), 256, 0, stream>>>(Ab, At, deg_s);
  transpose2_to_bf16<float><<<632 + 2528, 256, 0, stream>>>(
      h_s0, N_S, hsT, KS_PAD, 79, 632,
      r_em, N_R, hrT, KR_PAD, 316);
  transpose_weights<<<dim3(8, 8, 12), 256, 0, stream>>>(Wr, Ws, Vr, Vs, WT);

  const int ktA = KS_PAD / 64;  // 79
  const int ktT = KR_PAD / 64;  // 316

  // ---- layers ----
  int cur = 0;
  for (int l = 0; l < 3; ++l) {
    bf16_t* WrT = WT + ((size_t)l * 4 + 0) * DD * DD;
    bf16_t* WsT = WT + ((size_t)l * 4 + 1) * DD * DD;
    bf16_t* VrT = WT + ((size_t)l * 4 + 2) * DD * DD;
    bf16_t* VsT = WT + ((size_t)l * 4 + 3) * DD * DD;

    if (l < 2) {
      // fused big GEMM: job1 = m_s (Aᵀ@h_r, K=20224, z=7, long blocks first),
      //                 job2 = m_r (A@h_s, K=5056, z=3). 280+474 = 754 blocks.
      gemm256d<<<280 + 474, 512, 0, stream>>>(
          At, hrT, KR_PAD, ktT, 46, part_s, ps_s, 40, 280,
          Ab, hsT, KS_PAD, ktA, 27, part_r, ps_r, 158);
      combine2<<<5056 + 1280, 256, 0, stream>>>(
          part_r, 3, ps_r, deg_r, N_R, mr_b, 5056,
          part_s, 7, ps_s, deg_s, N_S, ms_b);
      // fused dense: h_r' = relu(m_r@Ws + h_r@Wr); h_s' = relu(m_s@Vr + h_s@Vs)
      gemm64_dual<<<632 + 160, 256, 0, stream>>>(
          mr_b, WsT, hr_b[cur], WrT, hr_b[1 - cur], N_R, nullptr, 158, 632,
          ms_b, VrT, hs_b[cur], VsT, hs_b[1 - cur], N_S, 40);
      // fused transposes for next layer's B operands
      transpose2_to_bf16<bf16_t><<<2528 + 632, 256, 0, stream>>>(
          hr_b[1 - cur], N_R, hrT, KR_PAD, 316, 2528,
          hs_b[1 - cur], N_S, hsT, KS_PAD, 79);
    } else {
      gemm256d<<<474, 512, 0, stream>>>(
          Ab, hsT, KS_PAD, ktA, 27, part_r, ps_r, 158, 474,
          Ab, hsT, KS_PAD, ktA, 27, part_r, ps_r, 158);
      combine2<<<5056, 256, 0, stream>>>(
          part_r, 3, ps_r, deg_r, N_R, mr_b, 5056,
          part_r, 3, ps_r, deg_r, N_R, mr_b);
      gemm64_dual<<<632, 256, 0, stream>>>(
          mr_b, WsT, hr_b[cur], WrT, hr_b[1 - cur], N_R, out, 158, 632,
          mr_b, WsT, hr_b[cur], WrT, hr_b[1 - cur], N_R, 158);
    }
    cur = 1 - cur;
  }
}